// Round 4
// baseline (293.094 us; speedup 1.0000x reference)
//
#include <hip/hip_runtime.h>
#include <hip/hip_bf16.h>
#include <math.h>

// GAT forward, N=4096, nfeat=512, nhid=64, nheads=8, nout=56, f32 in/out.
// Split-bf16 (hi+lo, 3 products) MFMA for all big GEMMs.
// R4 vs R3 (R3 was VALU-bound at 2 waves/SIMD: MfmaUtil 21 / VALU 54 / occ 18%):
//  - attn3: 256-thr blocks (4 waves x 16 rows) -> 4 blk/CU (50% occ ceiling);
//    global_load_lds 16B async staging (no reg round-trip, no copy VALU);
//    w-gen: exp2-domain scores (s1,s2 pre-scaled by log2e in producers),
//    round-half-up split ((u+0x8000)&0xFFFF0000) + exact lo + shift/or pack
//    (~4.5 VALU/value vs ~14 with __float2bfloat16 RTN; same ~2^-17 error).
//  - gemm_fused: epilogue emits swizzled bf16 image + s1L/s2L directly
//    (sv_kernel + conv_h kernels and ALL h_all f32 global traffic eliminated).
//  - l2prep: fuses h2k + sv + conv_h for layer 2.
//  - 9 kernel launches (was 13).
// Workspace ~29.5 MB (x_hi/x_lo aliased inside pO; pd shared L1/L2).

#define GN 4096
#define GNH 8
#define LOG2E 1.4426950408889634f

typedef __bf16 bf16x8 __attribute__((ext_vector_type(8)));
typedef float f32x4 __attribute__((ext_vector_type(4)));

__device__ inline void bf16split(float v, unsigned short& hi, unsigned short& lo) {
    __hip_bfloat16 h = __float2bfloat16(v);
    float hb = __bfloat162float(h);
    __hip_bfloat16 l = __float2bfloat16(v - hb);
    hi = *(unsigned short*)&h;
    lo = *(unsigned short*)&l;
}

// round-half-up hi/lo split + pack two values into (hi-pack, lo-pack) u32s
__device__ inline void split_pack2(float w0, float w1, unsigned& hp, unsigned& lp) {
    unsigned u0 = __float_as_uint(w0) + 0x8000u;
    unsigned u1 = __float_as_uint(w1) + 0x8000u;
    float l0 = w0 - __uint_as_float(u0 & 0xFFFF0000u);
    float l1 = w1 - __uint_as_float(u1 & 0xFFFF0000u);
    hp = (u1 & 0xFFFF0000u) | (u0 >> 16);
    lp = (__float_as_uint(l1) & 0xFFFF0000u) | (__float_as_uint(l0) >> 16);
}

__global__ __launch_bounds__(256) void pack_adj(const int* __restrict__ adj,
                                                unsigned long long* __restrict__ adjb) {
    int gid = blockIdx.x * 256 + threadIdx.x;        // over 4096*4096
    unsigned long long m = __ballot(adj[gid] > 0);
    if ((threadIdx.x & 63) == 0) adjb[gid >> 6] = m;
}

// x [4096][512] f32 -> x_hi/x_lo bf16 same layout
__global__ __launch_bounds__(256) void conv_x(const float* __restrict__ x,
                                              unsigned short* __restrict__ xh,
                                              unsigned short* __restrict__ xl) {
    int gid = blockIdx.x * 256 + threadIdx.x;        // over 4096*512
    unsigned short h, l;
    bf16split(x[gid], h, l);
    xh[gid] = h; xl[gid] = l;
}

// Ws [8][512][64] -> WT_hi/lo [8][64][512] bf16 (transposed). grid 64 blocks.
__global__ __launch_bounds__(256) void conv_wt(const float* __restrict__ Ws,
                                               unsigned short* __restrict__ wth,
                                               unsigned short* __restrict__ wtl) {
    int head = blockIdx.x >> 3;
    int k0 = (blockIdx.x & 7) * 64;
    for (int it = 0; it < 16; ++it) {
        int e = threadIdx.x + it * 256;              // over 64x64
        int k = k0 + (e >> 6), f = e & 63;
        unsigned short h, l;
        bf16split(Ws[((size_t)head * 512 + k) * 64 + f], h, l);
        wth[(size_t)head * 32768 + f * 512 + k] = h;
        wtl[(size_t)head * 32768 + f * 512 + k] = l;
    }
}

// h = x @ Ws[head]; epilogue emits swizzled bf16 image (hi/lo) + s1L/s2L
// (pre-scaled by log2e). grid (64 i-tiles, 8 heads), 256 thr.
// Image unit (f, c) at shorts offset f*64 + ((c^(f&7))*8), elements j=c*8+q.
__global__ __launch_bounds__(256) void gemm_fused(const unsigned short* __restrict__ xh,
                                                  const unsigned short* __restrict__ xl,
                                                  const unsigned short* __restrict__ wth,
                                                  const unsigned short* __restrict__ wtl,
                                                  const float* __restrict__ As,
                                                  unsigned short* __restrict__ imgh,
                                                  unsigned short* __restrict__ imgl,
                                                  float* __restrict__ s1L,
                                                  float* __restrict__ s2L) {
    __shared__ __align__(16) unsigned short smem[4][64 * 72];
    unsigned short* xAh = smem[0];
    unsigned short* xAl = smem[1];
    unsigned short* wBh = smem[2];
    unsigned short* wBl = smem[3];
    const int tid = threadIdx.x;
    const int head = blockIdx.y;
    const int i0 = blockIdx.x * 64;
    const unsigned short* wh = wth + (size_t)head * 32768;
    const unsigned short* wl = wtl + (size_t)head * 32768;
    const int lane = tid & 63, wv_ = tid >> 6;
    const int mi = (wv_ & 1) * 32, fi = (wv_ >> 1) * 32;
    const int row = lane & 15, quad = lane >> 4;
    f32x4 acc[2][2] = {};
    const int e0 = tid * 8, e1 = e0 + 2048;
    const int r0 = e0 >> 6, o0 = e0 & 63, r1 = e1 >> 6, o1 = e1 & 63;
    for (int k0 = 0; k0 < 512; k0 += 64) {
        __syncthreads();
        *(uint4*)&xAh[r0 * 72 + o0] = *(const uint4*)&xh[(size_t)(i0 + r0) * 512 + k0 + o0];
        *(uint4*)&xAh[r1 * 72 + o1] = *(const uint4*)&xh[(size_t)(i0 + r1) * 512 + k0 + o1];
        *(uint4*)&xAl[r0 * 72 + o0] = *(const uint4*)&xl[(size_t)(i0 + r0) * 512 + k0 + o0];
        *(uint4*)&xAl[r1 * 72 + o1] = *(const uint4*)&xl[(size_t)(i0 + r1) * 512 + k0 + o1];
        *(uint4*)&wBh[r0 * 72 + o0] = *(const uint4*)&wh[(size_t)r0 * 512 + k0 + o0];
        *(uint4*)&wBh[r1 * 72 + o1] = *(const uint4*)&wh[(size_t)r1 * 512 + k0 + o1];
        *(uint4*)&wBl[r0 * 72 + o0] = *(const uint4*)&wl[(size_t)r0 * 512 + k0 + o0];
        *(uint4*)&wBl[r1 * 72 + o1] = *(const uint4*)&wl[(size_t)r1 * 512 + k0 + o1];
        __syncthreads();
        #pragma unroll
        for (int ks = 0; ks < 2; ++ks) {
            const int ko = ks * 32 + quad * 8;
            bf16x8 ah[2], al[2], bh[2], bl[2];
            #pragma unroll
            for (int t = 0; t < 2; ++t) {
                ah[t] = *(const bf16x8*)&xAh[(mi + t * 16 + row) * 72 + ko];
                al[t] = *(const bf16x8*)&xAl[(mi + t * 16 + row) * 72 + ko];
                bh[t] = *(const bf16x8*)&wBh[(fi + t * 16 + row) * 72 + ko];
                bl[t] = *(const bf16x8*)&wBl[(fi + t * 16 + row) * 72 + ko];
            }
            #pragma unroll
            for (int mt = 0; mt < 2; ++mt)
                #pragma unroll
                for (int nt = 0; nt < 2; ++nt) {
                    acc[mt][nt] = __builtin_amdgcn_mfma_f32_16x16x32_bf16(ah[mt], bh[nt], acc[mt][nt], 0, 0, 0);
                    acc[mt][nt] = __builtin_amdgcn_mfma_f32_16x16x32_bf16(al[mt], bh[nt], acc[mt][nt], 0, 0, 0);
                    acc[mt][nt] = __builtin_amdgcn_mfma_f32_16x16x32_bf16(ah[mt], bl[nt], acc[mt][nt], 0, 0, 0);
                }
        }
    }
    // ---- fused epilogue ----
    __syncthreads();
    float* ht = (float*)&smem[0][0];                 // 64 x 68 f32 (17.4 KB, fits)
    #pragma unroll
    for (int mt = 0; mt < 2; ++mt)
        #pragma unroll
        for (int nt = 0; nt < 2; ++nt)
            #pragma unroll
            for (int r = 0; r < 4; ++r)
                ht[(mi + mt * 16 + quad * 4 + r) * 68 + fi + nt * 16 + row] = acc[mt][nt][r];
    __syncthreads();
    {   // s1/s2 (pre-scaled by log2e): thread t -> row t>>2, seg (t&3)*16
        const int rrow = tid >> 2, seg = (tid & 3) * 16;
        const float* ah = As + head * 128;
        float p1 = 0.f, p2 = 0.f;
        #pragma unroll
        for (int c = 0; c < 16; ++c) {
            float v = ht[rrow * 68 + seg + c];
            p1 += v * ah[seg + c];
            p2 += v * ah[64 + seg + c];
        }
        p1 += __shfl_xor(p1, 1); p1 += __shfl_xor(p1, 2);
        p2 += __shfl_xor(p2, 1); p2 += __shfl_xor(p2, 2);
        if ((tid & 3) == 0) {
            s1L[head * GN + i0 + rrow] = p1 * LOG2E;
            s2L[head * GN + i0 + rrow] = p2 * LOG2E;
        }
    }
    {   // swizzled image emit
        const int f = tid >> 2;
        size_t base = ((size_t)head * 64 + blockIdx.x) * 4096 + (size_t)f * 64;
        #pragma unroll
        for (int p = 0; p < 2; ++p) {
            int c = (tid & 3) * 2 + p;
            unsigned hp[4], lp[4];
            #pragma unroll
            for (int pp = 0; pp < 4; ++pp)
                split_pack2(ht[(c * 8 + 2 * pp) * 68 + f], ht[(c * 8 + 2 * pp + 1) * 68 + f],
                            hp[pp], lp[pp]);
            int off = (c ^ (f & 7)) * 8;
            *(uint4*)&imgh[base + off] = *(uint4*)hp;
            *(uint4*)&imgl[base + off] = *(uint4*)lp;
        }
    }
}

// Fused masked-softmax attention; w built in A-frag registers in exp2 domain.
// 256 thr = 4 waves x 16 rows (mt=1, nt=4); tile 64 rows x 64 j.
// global_load_lds async staging of pre-swizzled image; double-buffered.
// grid (64 i-tiles, GNHEADS*NCHUNK). Raw partial O + denom per slice.
template <int NCHUNK>
__global__ __launch_bounds__(256, 4) void attn3(const unsigned short* __restrict__ imgh,
                                                const unsigned short* __restrict__ imgl,
                                                const float* __restrict__ s1g,
                                                const float* __restrict__ s2g,
                                                const unsigned long long* __restrict__ adjb,
                                                float* __restrict__ pO,
                                                float* __restrict__ pd) {
    __shared__ __align__(16) unsigned short hb[2][8192];   // [buf][hi 4096 | lo 4096]
    const int tid = threadIdx.x;
    const int lane = tid & 63, wv = tid >> 6;
    const int row = lane & 15, quad = lane >> 4;
    const int head = blockIdx.y / NCHUNK;
    const int chunk = blockIdx.y % NCHUNK;
    const int i0 = blockIdx.x * 64;
    const int jb = chunk * (GN / NCHUNK);
    const int njt = (GN / NCHUNK) / 64;
    const int jt0 = jb >> 6;
    const unsigned short* ih = imgh + (size_t)head * (64 * GN);
    const unsigned short* il = imgl + (size_t)head * (64 * GN);
    const float* s2h = s2g + head * GN;
    const int gr = i0 + wv * 16 + row;
    const float s1v = s1g[head * GN + gr];
    const unsigned long long* adjr = adjb + (size_t)gr * 64 + jt0;

    f32x4 acc[4] = {};
    float den = 0.f;

    #define STAGE(buf, T)                                                                  \
        do {                                                                               \
            const unsigned short* gh_ = ih + (size_t)(T) * 4096;                           \
            const unsigned short* gl_ = il + (size_t)(T) * 4096;                           \
            _Pragma("unroll")                                                              \
            for (int c_ = 0; c_ < 2; ++c_)                                                 \
                __builtin_amdgcn_global_load_lds(                                          \
                    (const __attribute__((address_space(1))) unsigned int*)(gh_ + c_ * 2048 + tid * 8), \
                    (__attribute__((address_space(3))) unsigned int*)&hb[buf][c_ * 2048 + tid * 8],     \
                    16, 0, 0);                                                             \
            _Pragma("unroll")                                                              \
            for (int c_ = 0; c_ < 2; ++c_)                                                 \
                __builtin_amdgcn_global_load_lds(                                          \
                    (const __attribute__((address_space(1))) unsigned int*)(gl_ + c_ * 2048 + tid * 8), \
                    (__attribute__((address_space(3))) unsigned int*)&hb[buf][4096 + c_ * 2048 + tid * 8], \
                    16, 0, 0);                                                             \
        } while (0)

    STAGE(0, jt0);
    for (int jt = 0; jt < njt; ++jt) {
        __syncthreads();                             // drains loads into buf cur
        const int cur = jt & 1;
        if (jt + 1 < njt) STAGE(cur ^ 1, jt0 + jt + 1);
        const int j0 = jb + jt * 64;
        const unsigned long long wd = adjr[jt];
        #pragma unroll
        for (int ks = 0; ks < 2; ++ks) {
            const int kb = ks * 32 + quad * 8;
            float4 sa = *(const float4*)&s2h[j0 + kb];
            float4 sb = *(const float4*)&s2h[j0 + kb + 4];
            const float s2v[8] = {sa.x, sa.y, sa.z, sa.w, sb.x, sb.y, sb.z, sb.w};
            const unsigned bits = (unsigned)(wd >> kb) & 0xFFu;
            union { unsigned u[4]; bf16x8 v; } hfr, lfr;
            #pragma unroll
            for (int p = 0; p < 4; ++p) {
                float t0 = s1v + s2v[2 * p];
                float t1 = s1v + s2v[2 * p + 1];
                float e0 = exp2f(fmaxf(t0, 0.2f * t0));
                float e1 = exp2f(fmaxf(t1, 0.2f * t1));
                float w0 = ((bits >> (2 * p)) & 1u) ? e0 : 0.f;
                float w1 = ((bits >> (2 * p + 1)) & 1u) ? e1 : 0.f;
                den += w0 + w1;
                split_pack2(w0, w1, hfr.u[p], lfr.u[p]);
            }
            #pragma unroll
            for (int nt = 0; nt < 4; ++nt) {
                const int f = nt * 16 + row;
                const int off = f * 64 + (((ks * 4 + quad) ^ (f & 7)) * 8);
                bf16x8 bh = *(const bf16x8*)&hb[cur][off];
                bf16x8 bl = *(const bf16x8*)&hb[cur][4096 + off];
                acc[nt] = __builtin_amdgcn_mfma_f32_16x16x32_bf16(hfr.v, bh, acc[nt], 0, 0, 0);
                acc[nt] = __builtin_amdgcn_mfma_f32_16x16x32_bf16(lfr.v, bh, acc[nt], 0, 0, 0);
                acc[nt] = __builtin_amdgcn_mfma_f32_16x16x32_bf16(hfr.v, bl, acc[nt], 0, 0, 0);
            }
        }
    }
    #undef STAGE
    // row denominators: lanes {l, l^16, l^32, l^48} share a row
    den += __shfl_xor(den, 16);
    den += __shfl_xor(den, 32);
    float* o = pO + (size_t)blockIdx.y * (GN * 64);
    #pragma unroll
    for (int r = 0; r < 4; ++r) {
        const int grow = i0 + wv * 16 + quad * 4 + r;
        #pragma unroll
        for (int nt = 0; nt < 4; ++nt)
            o[(size_t)grow * 64 + nt * 16 + row] = acc[nt][r];
    }
    if (lane < 16) pd[blockIdx.y * GN + i0 + wv * 16 + lane] = den;
}

// combine L1 chunk partials per head, /denom, elu, mean over heads -> z
__global__ __launch_bounds__(256) void zred2(const float* __restrict__ pO,
                                             const float* __restrict__ pd,
                                             float* __restrict__ z) {
    int idx = blockIdx.x * 256 + threadIdx.x;        // over 4096*64
    int i = idx >> 6;
    float s = 0.f;
    #pragma unroll
    for (int hd = 0; hd < GNH; ++hd) {
        float o = pO[(size_t)(2 * hd) * (GN * 64) + idx] + pO[(size_t)(2 * hd + 1) * (GN * 64) + idx];
        float d = pd[(2 * hd) * GN + i] + pd[(2 * hd + 1) * GN + i];
        float v = o / d;
        s += v > 0.f ? v : expm1f(v);
    }
    z[idx] = s * 0.125f;
}

// layer-2 prep: h2p = z @ W_out (56 cols, zero-pad to 64) -> s1b/s2b (exp2
// domain) + swizzled bf16 image. grid 64 blocks (i-tiles), 256 thr.
__global__ __launch_bounds__(256) void l2prep(const float* __restrict__ z,
                                              const float* __restrict__ Wo,
                                              const float* __restrict__ ao,
                                              unsigned short* __restrict__ img2h,
                                              unsigned short* __restrict__ img2l,
                                              float* __restrict__ s1bL,
                                              float* __restrict__ s2bL) {
    __shared__ __align__(16) float zt[64 * 68];
    __shared__ float Wl[64 * 57];
    const int tid = threadIdx.x;
    const int i0 = blockIdx.x * 64;
    #pragma unroll
    for (int it = 0; it < 4; ++it) {
        int e = (tid + it * 256) * 4;
        int r = e >> 6, f = e & 63;
        *(float4*)&zt[r * 68 + f] = *(const float4*)&z[(size_t)(i0 + r) * 64 + f];
    }
    for (int idx = tid; idx < 64 * 56; idx += 256) {
        int k = idx / 56, c = idx - k * 56;
        Wl[k * 57 + c] = Wo[idx];
    }
    __syncthreads();
    const int rrow = tid >> 2, seg = (tid & 3) * 16;
    float hreg[16];
    #pragma unroll
    for (int c = 0; c < 16; ++c) hreg[c] = 0.f;
    for (int k0 = 0; k0 < 64; k0 += 4) {
        float4 zv = *(const float4*)&zt[rrow * 68 + k0];
        #pragma unroll
        for (int c = 0; c < 16; ++c) {
            int col = seg + c;
            if (col < 56)
                hreg[c] += zv.x * Wl[k0 * 57 + col] + zv.y * Wl[(k0 + 1) * 57 + col] +
                           zv.z * Wl[(k0 + 2) * 57 + col] + zv.w * Wl[(k0 + 3) * 57 + col];
        }
    }
    {   // s1b/s2b (pre-scaled by log2e)
        float p1 = 0.f, p2 = 0.f;
        #pragma unroll
        for (int c = 0; c < 16; ++c) {
            int col = seg + c;
            if (col < 56) {
                p1 += hreg[c] * ao[col];
                p2 += hreg[c] * ao[56 + col];
            }
        }
        p1 += __shfl_xor(p1, 1); p1 += __shfl_xor(p1, 2);
        p2 += __shfl_xor(p2, 1); p2 += __shfl_xor(p2, 2);
        if ((tid & 3) == 0) {
            s1bL[i0 + rrow] = p1 * LOG2E;
            s2bL[i0 + rrow] = p2 * LOG2E;
        }
    }
    __syncthreads();
    #pragma unroll
    for (int c = 0; c < 16; ++c) zt[rrow * 68 + seg + c] = (seg + c < 56) ? hreg[c] : 0.f;
    __syncthreads();
    {   // swizzled image emit (head index 0)
        const int f = tid >> 2;
        size_t base = (size_t)blockIdx.x * 4096 + (size_t)f * 64;
        #pragma unroll
        for (int p = 0; p < 2; ++p) {
            int c = (tid & 3) * 2 + p;
            unsigned hp[4], lp[4];
            #pragma unroll
            for (int pp = 0; pp < 4; ++pp)
                split_pack2(zt[(c * 8 + 2 * pp) * 68 + f], zt[(c * 8 + 2 * pp + 1) * 68 + f],
                            hp[pp], lp[pp]);
            int off = (c ^ (f & 7)) * 8;
            *(uint4*)&img2h[base + off] = *(uint4*)hp;
            *(uint4*)&img2l[base + off] = *(uint4*)lp;
        }
    }
}

// combine 16 j-chunk partials, /denom, elu, softmax(56) -> out
__global__ __launch_bounds__(256) void fink2(const float* __restrict__ pO,
                                             const float* __restrict__ pd,
                                             float* __restrict__ out) {
    const int lane = threadIdx.x & 63;
    const int w = threadIdx.x >> 6;
    const int i = blockIdx.x * 4 + w;
    float o = 0.f, d = 0.f;
    #pragma unroll
    for (int c = 0; c < 16; ++c) d += pd[c * GN + i];
    if (lane < 56) {
        #pragma unroll
        for (int c = 0; c < 16; ++c) o += pO[(size_t)c * (GN * 64) + (size_t)i * 64 + lane];
    }
    float v = -1e30f;
    if (lane < 56) {
        float t = o / d;
        v = t > 0.f ? t : expm1f(t);
    }
    float m = v;
    #pragma unroll
    for (int off = 32; off; off >>= 1) m = fmaxf(m, __shfl_down(m, off));
    m = __shfl(m, 0);
    float p = (lane < 56) ? __expf(v - m) : 0.f;
    float s = p;
    #pragma unroll
    for (int off = 32; off; off >>= 1) s += __shfl_down(s, off);
    s = __shfl(s, 0);
    if (lane < 56) out[(size_t)i * 56 + lane] = p / s;
}

extern "C" void kernel_launch(void* const* d_in, const int* in_sizes, int n_in,
                              void* d_out, int out_size, void* d_ws, size_t ws_size,
                              hipStream_t stream) {
    const float* x    = (const float*)d_in[0];
    const int*   adj  = (const int*)d_in[1];
    const float* Ws   = (const float*)d_in[2];
    const float* As   = (const float*)d_in[3];
    const float* Wo   = (const float*)d_in[4];
    const float* ao   = (const float*)d_in[5];
    float* out = (float*)d_out;

    char* ws = (char*)d_ws;
    unsigned long long* adjb = (unsigned long long*)(ws + 0);           // 2 MB
    unsigned short* img1h = (unsigned short*)(ws + 2097152);            // 4 MB
    unsigned short* img1l = (unsigned short*)(ws + 6291456);            // 4 MB
    float* pO    = (float*)(ws + 10485760);                             // 16 MB (slices)
    unsigned short* x_hi = (unsigned short*)(ws + 18874368);            // 4 MB (inside pO, pre-attn only)
    unsigned short* x_lo = (unsigned short*)(ws + 23068672);            // 4 MB (inside pO, pre-attn only)
    float* pd    = (float*)(ws + 27262976);                             // 256 KB (shared L1/L2)
    float* s1L   = (float*)(ws + 27525120);                             // 128 KB
    float* s2L   = (float*)(ws + 27656192);                             // 128 KB
    float* z     = (float*)(ws + 27787264);                             // 1 MB
    unsigned short* img2h = (unsigned short*)(ws + 28835840);           // 512 KB
    unsigned short* img2l = (unsigned short*)(ws + 29360128);           // 512 KB
    float* s1bL  = (float*)(ws + 29884416);                             // 16 KB
    float* s2bL  = (float*)(ws + 29900800);                             // 16 KB
    unsigned short* WT_hi = (unsigned short*)(ws + 29917184);           // 512 KB
    unsigned short* WT_lo = (unsigned short*)(ws + 30441472);           // 512 KB
    // total 30965760 B ~= 29.5 MB

    pack_adj<<<65536, 256, 0, stream>>>(adj, adjb);
    conv_x<<<8192, 256, 0, stream>>>(x, x_hi, x_lo);
    conv_wt<<<64, 256, 0, stream>>>(Ws, WT_hi, WT_lo);
    gemm_fused<<<dim3(64, 8), 256, 0, stream>>>(x_hi, x_lo, WT_hi, WT_lo, As,
                                                img1h, img1l, s1L, s2L);
    attn3<2><<<dim3(64, 16), 256, 0, stream>>>(img1h, img1l, s1L, s2L, adjb, pO, pd);
    zred2<<<1024, 256, 0, stream>>>(pO, pd, z);
    l2prep<<<64, 256, 0, stream>>>(z, Wo, ao, img2h, img2l, s1bL, s2bL);
    attn3<16><<<dim3(64, 16), 256, 0, stream>>>(img2h, img2l, s1bL, s2bL, adjb, pO, pd);
    fink2<<<1024, 256, 0, stream>>>(pO, pd, out);
}

// Round 5
// 262.368 us; speedup vs baseline: 1.1171x; 1.1171x over previous
//
#include <hip/hip_runtime.h>
#include <hip/hip_bf16.h>
#include <math.h>

// GAT forward, N=4096, nfeat=512, nhid=64, nheads=8, nout=56, f32 in/out.
// Split-bf16 (hi+lo, 3 products) MFMA for all big GEMMs.
// R5 vs R4 (R4 regressed: exp2f lowered to OCML slow path => ~44 VALU/value,
// VALUBusy 68% of 112us):
//  - FAST_EXP2 = __builtin_amdgcn_exp2f (raw v_exp_f32) w/ __expf fallback.
//  - split_pack2 uses v_perm_b32 (__builtin_amdgcn_perm) for bf16 packing.
//  - adjacency mask applied as float multiply (bfe+cvt+mul, no vcc chains).
//  - gemm_fused grid (head, itile) so consecutive blocks share x-tile in L2.
//  - pack_adj 4 elems/lane; conv_x float4.
// Workspace ~29.5 MB.

#define GN 4096
#define GNH 8
#define LOG2E 1.4426950408889634f

typedef __bf16 bf16x8 __attribute__((ext_vector_type(8)));
typedef float f32x4 __attribute__((ext_vector_type(4)));

#if defined(__has_builtin)
#if __has_builtin(__builtin_amdgcn_exp2f)
#define FAST_EXP2(x) __builtin_amdgcn_exp2f(x)
#endif
#if __has_builtin(__builtin_amdgcn_perm)
#define FAST_PERM(a, b, s) __builtin_amdgcn_perm((a), (b), (s))
#endif
#endif
#ifndef FAST_EXP2
#define FAST_EXP2(x) __expf((x)*0.6931471805599453f)
#endif
#ifndef FAST_PERM
__device__ inline unsigned FAST_PERM(unsigned a, unsigned b, unsigned) {
    return (a & 0xFFFF0000u) | (b >> 16);
}
#endif

__device__ inline void bf16split(float v, unsigned short& hi, unsigned short& lo) {
    __hip_bfloat16 h = __float2bfloat16(v);
    float hb = __bfloat162float(h);
    __hip_bfloat16 l = __float2bfloat16(v - hb);
    hi = *(unsigned short*)&h;
    lo = *(unsigned short*)&l;
}

// round-half-up hi/lo split + pack two values into (hi-pack, lo-pack) u32s
// result: low 16 = value0's bf16, high 16 = value1's bf16
__device__ inline void split_pack2(float w0, float w1, unsigned& hp, unsigned& lp) {
    unsigned u0 = __float_as_uint(w0) + 0x8000u;
    unsigned u1 = __float_as_uint(w1) + 0x8000u;
    float l0 = w0 - __uint_as_float(u0 & 0xFFFF0000u);
    float l1 = w1 - __uint_as_float(u1 & 0xFFFF0000u);
    hp = FAST_PERM(u1, u0, 0x07060302u);             // [u1.b3,u1.b2,u0.b3,u0.b2]
    lp = FAST_PERM(__float_as_uint(l1), __float_as_uint(l0), 0x07060302u);
}

// adj int32 -> bitmask; 4 elements per lane. grid N*N/1024.
__global__ __launch_bounds__(256) void pack_adj(const int* __restrict__ adj,
                                                unsigned long long* __restrict__ adjb) {
    const int wv = threadIdx.x >> 6, lane = threadIdx.x & 63;
    const size_t ebase = ((size_t)blockIdx.x * 4 + wv) * 256;
    unsigned long long m[4];
    #pragma unroll
    for (int e = 0; e < 4; ++e)
        m[e] = __ballot(adj[ebase + e * 64 + lane] > 0);
    if (lane == 0) {
        #pragma unroll
        for (int e = 0; e < 4; ++e) adjb[(ebase >> 6) + e] = m[e];
    }
}

// x [4096][512] f32 -> x_hi/x_lo bf16 same layout; float4 per thread
__global__ __launch_bounds__(256) void conv_x(const float* __restrict__ x,
                                              unsigned short* __restrict__ xh,
                                              unsigned short* __restrict__ xl) {
    int gid = blockIdx.x * 256 + threadIdx.x;        // over 4096*512/4
    float4 v = *(const float4*)&x[(size_t)gid * 4];
    unsigned hp[2], lp[2];
    split_pack2(v.x, v.y, hp[0], lp[0]);
    split_pack2(v.z, v.w, hp[1], lp[1]);
    *(uint2*)&xh[(size_t)gid * 4] = *(uint2*)hp;
    *(uint2*)&xl[(size_t)gid * 4] = *(uint2*)lp;
}

// Ws [8][512][64] -> WT_hi/lo [8][64][512] bf16 (transposed). grid 64 blocks.
__global__ __launch_bounds__(256) void conv_wt(const float* __restrict__ Ws,
                                               unsigned short* __restrict__ wth,
                                               unsigned short* __restrict__ wtl) {
    int head = blockIdx.x >> 3;
    int k0 = (blockIdx.x & 7) * 64;
    for (int it = 0; it < 16; ++it) {
        int e = threadIdx.x + it * 256;              // over 64x64
        int k = k0 + (e >> 6), f = e & 63;
        unsigned short h, l;
        bf16split(Ws[((size_t)head * 512 + k) * 64 + f], h, l);
        wth[(size_t)head * 32768 + f * 512 + k] = h;
        wtl[(size_t)head * 32768 + f * 512 + k] = l;
    }
}

// h = x @ Ws[head]; epilogue emits swizzled bf16 image (hi/lo) + s1L/s2L
// (pre-scaled by log2e). grid (8 heads, 64 i-tiles), 256 thr.
// Image unit (f, c) at shorts offset f*64 + ((c^(f&7))*8), elements j=c*8+q.
__global__ __launch_bounds__(256) void gemm_fused(const unsigned short* __restrict__ xh,
                                                  const unsigned short* __restrict__ xl,
                                                  const unsigned short* __restrict__ wth,
                                                  const unsigned short* __restrict__ wtl,
                                                  const float* __restrict__ As,
                                                  unsigned short* __restrict__ imgh,
                                                  unsigned short* __restrict__ imgl,
                                                  float* __restrict__ s1L,
                                                  float* __restrict__ s2L) {
    __shared__ __align__(16) unsigned short smem[4][64 * 72];
    unsigned short* xAh = smem[0];
    unsigned short* xAl = smem[1];
    unsigned short* wBh = smem[2];
    unsigned short* wBl = smem[3];
    const int tid = threadIdx.x;
    const int head = blockIdx.x;
    const int itile = blockIdx.y;
    const int i0 = itile * 64;
    const unsigned short* wh = wth + (size_t)head * 32768;
    const unsigned short* wl = wtl + (size_t)head * 32768;
    const int lane = tid & 63, wv_ = tid >> 6;
    const int mi = (wv_ & 1) * 32, fi = (wv_ >> 1) * 32;
    const int row = lane & 15, quad = lane >> 4;
    f32x4 acc[2][2] = {};
    const int e0 = tid * 8, e1 = e0 + 2048;
    const int r0 = e0 >> 6, o0 = e0 & 63, r1 = e1 >> 6, o1 = e1 & 63;
    for (int k0 = 0; k0 < 512; k0 += 64) {
        __syncthreads();
        *(uint4*)&xAh[r0 * 72 + o0] = *(const uint4*)&xh[(size_t)(i0 + r0) * 512 + k0 + o0];
        *(uint4*)&xAh[r1 * 72 + o1] = *(const uint4*)&xh[(size_t)(i0 + r1) * 512 + k0 + o1];
        *(uint4*)&xAl[r0 * 72 + o0] = *(const uint4*)&xl[(size_t)(i0 + r0) * 512 + k0 + o0];
        *(uint4*)&xAl[r1 * 72 + o1] = *(const uint4*)&xl[(size_t)(i0 + r1) * 512 + k0 + o1];
        *(uint4*)&wBh[r0 * 72 + o0] = *(const uint4*)&wh[(size_t)r0 * 512 + k0 + o0];
        *(uint4*)&wBh[r1 * 72 + o1] = *(const uint4*)&wh[(size_t)r1 * 512 + k0 + o1];
        *(uint4*)&wBl[r0 * 72 + o0] = *(const uint4*)&wl[(size_t)r0 * 512 + k0 + o0];
        *(uint4*)&wBl[r1 * 72 + o1] = *(const uint4*)&wl[(size_t)r1 * 512 + k0 + o1];
        __syncthreads();
        #pragma unroll
        for (int ks = 0; ks < 2; ++ks) {
            const int ko = ks * 32 + quad * 8;
            bf16x8 ah[2], al[2], bh[2], bl[2];
            #pragma unroll
            for (int t = 0; t < 2; ++t) {
                ah[t] = *(const bf16x8*)&xAh[(mi + t * 16 + row) * 72 + ko];
                al[t] = *(const bf16x8*)&xAl[(mi + t * 16 + row) * 72 + ko];
                bh[t] = *(const bf16x8*)&wBh[(fi + t * 16 + row) * 72 + ko];
                bl[t] = *(const bf16x8*)&wBl[(fi + t * 16 + row) * 72 + ko];
            }
            #pragma unroll
            for (int mt = 0; mt < 2; ++mt)
                #pragma unroll
                for (int nt = 0; nt < 2; ++nt) {
                    acc[mt][nt] = __builtin_amdgcn_mfma_f32_16x16x32_bf16(ah[mt], bh[nt], acc[mt][nt], 0, 0, 0);
                    acc[mt][nt] = __builtin_amdgcn_mfma_f32_16x16x32_bf16(al[mt], bh[nt], acc[mt][nt], 0, 0, 0);
                    acc[mt][nt] = __builtin_amdgcn_mfma_f32_16x16x32_bf16(ah[mt], bl[nt], acc[mt][nt], 0, 0, 0);
                }
        }
    }
    // ---- fused epilogue ----
    __syncthreads();
    float* ht = (float*)&smem[0][0];                 // 64 x 68 f32 (17.4 KB, fits)
    #pragma unroll
    for (int mt = 0; mt < 2; ++mt)
        #pragma unroll
        for (int nt = 0; nt < 2; ++nt)
            #pragma unroll
            for (int r = 0; r < 4; ++r)
                ht[(mi + mt * 16 + quad * 4 + r) * 68 + fi + nt * 16 + row] = acc[mt][nt][r];
    __syncthreads();
    {   // s1/s2 (pre-scaled by log2e): thread t -> row t>>2, seg (t&3)*16
        const int rrow = tid >> 2, seg = (tid & 3) * 16;
        const float* ah = As + head * 128;
        float p1 = 0.f, p2 = 0.f;
        #pragma unroll
        for (int c = 0; c < 16; ++c) {
            float v = ht[rrow * 68 + seg + c];
            p1 += v * ah[seg + c];
            p2 += v * ah[64 + seg + c];
        }
        p1 += __shfl_xor(p1, 1); p1 += __shfl_xor(p1, 2);
        p2 += __shfl_xor(p2, 1); p2 += __shfl_xor(p2, 2);
        if ((tid & 3) == 0) {
            s1L[head * GN + i0 + rrow] = p1 * LOG2E;
            s2L[head * GN + i0 + rrow] = p2 * LOG2E;
        }
    }
    {   // swizzled image emit
        const int f = tid >> 2;
        size_t base = ((size_t)head * 64 + itile) * 4096 + (size_t)f * 64;
        #pragma unroll
        for (int p = 0; p < 2; ++p) {
            int c = (tid & 3) * 2 + p;
            unsigned hp[4], lp[4];
            #pragma unroll
            for (int pp = 0; pp < 4; ++pp)
                split_pack2(ht[(c * 8 + 2 * pp) * 68 + f], ht[(c * 8 + 2 * pp + 1) * 68 + f],
                            hp[pp], lp[pp]);
            int off = (c ^ (f & 7)) * 8;
            *(uint4*)&imgh[base + off] = *(uint4*)hp;
            *(uint4*)&imgl[base + off] = *(uint4*)lp;
        }
    }
}

// Fused masked-softmax attention; w built in A-frag registers in exp2 domain.
// 256 thr = 4 waves x 16 rows (mt=1, nt=4); tile 64 rows x 64 j.
// global_load_lds async staging of pre-swizzled image; double-buffered.
// grid (64 i-tiles, GNHEADS*NCHUNK). Raw partial O + denom per slice.
template <int NCHUNK>
__global__ __launch_bounds__(256, 4) void attn3(const unsigned short* __restrict__ imgh,
                                                const unsigned short* __restrict__ imgl,
                                                const float* __restrict__ s1g,
                                                const float* __restrict__ s2g,
                                                const unsigned long long* __restrict__ adjb,
                                                float* __restrict__ pO,
                                                float* __restrict__ pd) {
    __shared__ __align__(16) unsigned short hb[2][8192];   // [buf][hi 4096 | lo 4096]
    const int tid = threadIdx.x;
    const int lane = tid & 63, wv = tid >> 6;
    const int row = lane & 15, quad = lane >> 4;
    const int head = blockIdx.y / NCHUNK;
    const int chunk = blockIdx.y % NCHUNK;
    const int i0 = blockIdx.x * 64;
    const int jb = chunk * (GN / NCHUNK);
    const int njt = (GN / NCHUNK) / 64;
    const int jt0 = jb >> 6;
    const unsigned short* ih = imgh + (size_t)head * (64 * GN);
    const unsigned short* il = imgl + (size_t)head * (64 * GN);
    const float* s2h = s2g + head * GN;
    const int gr = i0 + wv * 16 + row;
    const float s1v = s1g[head * GN + gr];
    const unsigned long long* adjr = adjb + (size_t)gr * 64 + jt0;

    f32x4 acc[4] = {};
    float den = 0.f;

    #define STAGE(buf, T)                                                                  \
        do {                                                                               \
            const unsigned short* gh_ = ih + (size_t)(T) * 4096;                           \
            const unsigned short* gl_ = il + (size_t)(T) * 4096;                           \
            _Pragma("unroll")                                                              \
            for (int c_ = 0; c_ < 2; ++c_)                                                 \
                __builtin_amdgcn_global_load_lds(                                          \
                    (const __attribute__((address_space(1))) unsigned int*)(gh_ + c_ * 2048 + tid * 8), \
                    (__attribute__((address_space(3))) unsigned int*)&hb[buf][c_ * 2048 + tid * 8],     \
                    16, 0, 0);                                                             \
            _Pragma("unroll")                                                              \
            for (int c_ = 0; c_ < 2; ++c_)                                                 \
                __builtin_amdgcn_global_load_lds(                                          \
                    (const __attribute__((address_space(1))) unsigned int*)(gl_ + c_ * 2048 + tid * 8), \
                    (__attribute__((address_space(3))) unsigned int*)&hb[buf][4096 + c_ * 2048 + tid * 8], \
                    16, 0, 0);                                                             \
        } while (0)

    STAGE(0, jt0);
    for (int jt = 0; jt < njt; ++jt) {
        __syncthreads();                             // drains loads into buf cur
        const int cur = jt & 1;
        if (jt + 1 < njt) STAGE(cur ^ 1, jt0 + jt + 1);
        const int j0 = jb + jt * 64;
        const unsigned long long wd = adjr[jt];
        #pragma unroll
        for (int ks = 0; ks < 2; ++ks) {
            const int kb = ks * 32 + quad * 8;
            float4 sa = *(const float4*)&s2h[j0 + kb];
            float4 sb = *(const float4*)&s2h[j0 + kb + 4];
            const float s2v[8] = {sa.x, sa.y, sa.z, sa.w, sb.x, sb.y, sb.z, sb.w};
            const unsigned bits = (unsigned)(wd >> kb) & 0xFFu;
            union { unsigned u[4]; bf16x8 v; } hfr, lfr;
            #pragma unroll
            for (int p = 0; p < 4; ++p) {
                float m0 = (float)((bits >> (2 * p)) & 1u);
                float m1 = (float)((bits >> (2 * p + 1)) & 1u);
                float t0 = s1v + s2v[2 * p];
                float t1 = s1v + s2v[2 * p + 1];
                float w0 = FAST_EXP2(fmaxf(t0, 0.2f * t0)) * m0;
                float w1 = FAST_EXP2(fmaxf(t1, 0.2f * t1)) * m1;
                den += w0 + w1;
                split_pack2(w0, w1, hfr.u[p], lfr.u[p]);
            }
            #pragma unroll
            for (int nt = 0; nt < 4; ++nt) {
                const int f = nt * 16 + row;
                const int off = f * 64 + (((ks * 4 + quad) ^ (f & 7)) * 8);
                bf16x8 bh = *(const bf16x8*)&hb[cur][off];
                bf16x8 bl = *(const bf16x8*)&hb[cur][4096 + off];
                acc[nt] = __builtin_amdgcn_mfma_f32_16x16x32_bf16(hfr.v, bh, acc[nt], 0, 0, 0);
                acc[nt] = __builtin_amdgcn_mfma_f32_16x16x32_bf16(lfr.v, bh, acc[nt], 0, 0, 0);
                acc[nt] = __builtin_amdgcn_mfma_f32_16x16x32_bf16(hfr.v, bl, acc[nt], 0, 0, 0);
            }
        }
    }
    #undef STAGE
    // row denominators: lanes {l, l^16, l^32, l^48} share a row
    den += __shfl_xor(den, 16);
    den += __shfl_xor(den, 32);
    float* o = pO + (size_t)blockIdx.y * (GN * 64);
    #pragma unroll
    for (int r = 0; r < 4; ++r) {
        const int grow = i0 + wv * 16 + quad * 4 + r;
        #pragma unroll
        for (int nt = 0; nt < 4; ++nt)
            o[(size_t)grow * 64 + nt * 16 + row] = acc[nt][r];
    }
    if (lane < 16) pd[blockIdx.y * GN + i0 + wv * 16 + lane] = den;
}

// combine L1 chunk partials per head, /denom, elu, mean over heads -> z
__global__ __launch_bounds__(256) void zred2(const float* __restrict__ pO,
                                             const float* __restrict__ pd,
                                             float* __restrict__ z) {
    int idx = blockIdx.x * 256 + threadIdx.x;        // over 4096*64
    int i = idx >> 6;
    float s = 0.f;
    #pragma unroll
    for (int hd = 0; hd < GNH; ++hd) {
        float o = pO[(size_t)(2 * hd) * (GN * 64) + idx] + pO[(size_t)(2 * hd + 1) * (GN * 64) + idx];
        float d = pd[(2 * hd) * GN + i] + pd[(2 * hd + 1) * GN + i];
        float v = o / d;
        s += v > 0.f ? v : expm1f(v);
    }
    z[idx] = s * 0.125f;
}

// layer-2 prep: h2p = z @ W_out (56 cols, zero-pad to 64) -> s1b/s2b (exp2
// domain) + swizzled bf16 image. grid 64 blocks (i-tiles), 256 thr.
__global__ __launch_bounds__(256) void l2prep(const float* __restrict__ z,
                                              const float* __restrict__ Wo,
                                              const float* __restrict__ ao,
                                              unsigned short* __restrict__ img2h,
                                              unsigned short* __restrict__ img2l,
                                              float* __restrict__ s1bL,
                                              float* __restrict__ s2bL) {
    __shared__ __align__(16) float zt[64 * 68];
    __shared__ float Wl[64 * 57];
    const int tid = threadIdx.x;
    const int i0 = blockIdx.x * 64;
    #pragma unroll
    for (int it = 0; it < 4; ++it) {
        int e = (tid + it * 256) * 4;
        int r = e >> 6, f = e & 63;
        *(float4*)&zt[r * 68 + f] = *(const float4*)&z[(size_t)(i0 + r) * 64 + f];
    }
    for (int idx = tid; idx < 64 * 56; idx += 256) {
        int k = idx / 56, c = idx - k * 56;
        Wl[k * 57 + c] = Wo[idx];
    }
    __syncthreads();
    const int rrow = tid >> 2, seg = (tid & 3) * 16;
    float hreg[16];
    #pragma unroll
    for (int c = 0; c < 16; ++c) hreg[c] = 0.f;
    for (int k0 = 0; k0 < 64; k0 += 4) {
        float4 zv = *(const float4*)&zt[rrow * 68 + k0];
        #pragma unroll
        for (int c = 0; c < 16; ++c) {
            int col = seg + c;
            if (col < 56)
                hreg[c] += zv.x * Wl[k0 * 57 + col] + zv.y * Wl[(k0 + 1) * 57 + col] +
                           zv.z * Wl[(k0 + 2) * 57 + col] + zv.w * Wl[(k0 + 3) * 57 + col];
        }
    }
    {   // s1b/s2b (pre-scaled by log2e)
        float p1 = 0.f, p2 = 0.f;
        #pragma unroll
        for (int c = 0; c < 16; ++c) {
            int col = seg + c;
            if (col < 56) {
                p1 += hreg[c] * ao[col];
                p2 += hreg[c] * ao[56 + col];
            }
        }
        p1 += __shfl_xor(p1, 1); p1 += __shfl_xor(p1, 2);
        p2 += __shfl_xor(p2, 1); p2 += __shfl_xor(p2, 2);
        if ((tid & 3) == 0) {
            s1bL[i0 + rrow] = p1 * LOG2E;
            s2bL[i0 + rrow] = p2 * LOG2E;
        }
    }
    __syncthreads();
    #pragma unroll
    for (int c = 0; c < 16; ++c) zt[rrow * 68 + seg + c] = (seg + c < 56) ? hreg[c] : 0.f;
    __syncthreads();
    {   // swizzled image emit (head index 0)
        const int f = tid >> 2;
        size_t base = (size_t)blockIdx.x * 4096 + (size_t)f * 64;
        #pragma unroll
        for (int p = 0; p < 2; ++p) {
            int c = (tid & 3) * 2 + p;
            unsigned hp[4], lp[4];
            #pragma unroll
            for (int pp = 0; pp < 4; ++pp)
                split_pack2(zt[(c * 8 + 2 * pp) * 68 + f], zt[(c * 8 + 2 * pp + 1) * 68 + f],
                            hp[pp], lp[pp]);
            int off = (c ^ (f & 7)) * 8;
            *(uint4*)&img2h[base + off] = *(uint4*)hp;
            *(uint4*)&img2l[base + off] = *(uint4*)lp;
        }
    }
}

// combine 16 j-chunk partials, /denom, elu, softmax(56) -> out
__global__ __launch_bounds__(256) void fink2(const float* __restrict__ pO,
                                             const float* __restrict__ pd,
                                             float* __restrict__ out) {
    const int lane = threadIdx.x & 63;
    const int w = threadIdx.x >> 6;
    const int i = blockIdx.x * 4 + w;
    float o = 0.f, d = 0.f;
    #pragma unroll
    for (int c = 0; c < 16; ++c) d += pd[c * GN + i];
    if (lane < 56) {
        #pragma unroll
        for (int c = 0; c < 16; ++c) o += pO[(size_t)c * (GN * 64) + (size_t)i * 64 + lane];
    }
    float v = -1e30f;
    if (lane < 56) {
        float t = o / d;
        v = t > 0.f ? t : expm1f(t);
    }
    float m = v;
    #pragma unroll
    for (int off = 32; off; off >>= 1) m = fmaxf(m, __shfl_down(m, off));
    m = __shfl(m, 0);
    float p = (lane < 56) ? __expf(v - m) : 0.f;
    float s = p;
    #pragma unroll
    for (int off = 32; off; off >>= 1) s += __shfl_down(s, off);
    s = __shfl(s, 0);
    if (lane < 56) out[(size_t)i * 56 + lane] = p / s;
}

extern "C" void kernel_launch(void* const* d_in, const int* in_sizes, int n_in,
                              void* d_out, int out_size, void* d_ws, size_t ws_size,
                              hipStream_t stream) {
    const float* x    = (const float*)d_in[0];
    const int*   adj  = (const int*)d_in[1];
    const float* Ws   = (const float*)d_in[2];
    const float* As   = (const float*)d_in[3];
    const float* Wo   = (const float*)d_in[4];
    const float* ao   = (const float*)d_in[5];
    float* out = (float*)d_out;

    char* ws = (char*)d_ws;
    unsigned long long* adjb = (unsigned long long*)(ws + 0);           // 2 MB
    unsigned short* img1h = (unsigned short*)(ws + 2097152);            // 4 MB
    unsigned short* img1l = (unsigned short*)(ws + 6291456);            // 4 MB
    float* pO    = (float*)(ws + 10485760);                             // 16 MB (slices)
    unsigned short* x_hi = (unsigned short*)(ws + 18874368);            // 4 MB (inside pO, pre-attn only)
    unsigned short* x_lo = (unsigned short*)(ws + 23068672);            // 4 MB (inside pO, pre-attn only)
    float* pd    = (float*)(ws + 27262976);                             // 256 KB (shared L1/L2)
    float* s1L   = (float*)(ws + 27525120);                             // 128 KB
    float* s2L   = (float*)(ws + 27656192);                             // 128 KB
    float* z     = (float*)(ws + 27787264);                             // 1 MB
    unsigned short* img2h = (unsigned short*)(ws + 28835840);           // 512 KB
    unsigned short* img2l = (unsigned short*)(ws + 29360128);           // 512 KB
    float* s1bL  = (float*)(ws + 29884416);                             // 16 KB
    float* s2bL  = (float*)(ws + 29900800);                             // 16 KB
    unsigned short* WT_hi = (unsigned short*)(ws + 29917184);           // 512 KB
    unsigned short* WT_lo = (unsigned short*)(ws + 30441472);           // 512 KB
    // total 30965760 B ~= 29.5 MB

    pack_adj<<<16384, 256, 0, stream>>>(adj, adjb);
    conv_x<<<2048, 256, 0, stream>>>(x, x_hi, x_lo);
    conv_wt<<<64, 256, 0, stream>>>(Ws, WT_hi, WT_lo);
    gemm_fused<<<dim3(8, 64), 256, 0, stream>>>(x_hi, x_lo, WT_hi, WT_lo, As,
                                                img1h, img1l, s1L, s2L);
    attn3<2><<<dim3(64, 16), 256, 0, stream>>>(img1h, img1l, s1L, s2L, adjb, pO, pd);
    zred2<<<1024, 256, 0, stream>>>(pO, pd, z);
    l2prep<<<64, 256, 0, stream>>>(z, Wo, ao, img2h, img2l, s1bL, s2bL);
    attn3<16><<<dim3(64, 16), 256, 0, stream>>>(img2h, img2l, s1bL, s2bL, adjb, pO, pd);
    fink2<<<1024, 256, 0, stream>>>(pO, pd, out);
}